// Round 2
// baseline (102.977 us; speedup 1.0000x reference)
//
#include <hip/hip_runtime.h>

#define M_TOT 32768
#define K_TOT 768
#define N_TOT 768

typedef int v4i __attribute__((ext_vector_type(4)));
typedef unsigned int v4u __attribute__((ext_vector_type(4)));

#define GLOAD_LDS(g, l) __builtin_amdgcn_global_load_lds( \
    (const __attribute__((address_space(1))) unsigned int*)(g), \
    (__attribute__((address_space(3))) unsigned int*)(l), 16, 0, 0)

// Pack 4 int32 (each holding an int8 value) into one dword of 4 bytes.
__device__ __forceinline__ unsigned pack4(v4i a) {
  unsigned lo = __builtin_amdgcn_perm((unsigned)a.y, (unsigned)a.x, 0x00000400u);
  unsigned hi = __builtin_amdgcn_perm((unsigned)a.w, (unsigned)a.z, 0x00000400u);
  return __builtin_amdgcn_perm(hi, lo, 0x05040100u);
}

// W[k][n] int32 -> W8T[n][k] int8 (transposed, packed)
__global__ __launch_bounds__(256) void pack_w_kernel(const int* __restrict__ W,
                                                     signed char* __restrict__ W8T) {
  __shared__ signed char t[64][72];
  const int k0 = blockIdx.x * 64, n0 = blockIdx.y * 64;
  for (int i = threadIdx.x; i < 4096; i += 256) {
    int k = i >> 6, n = i & 63;
    t[n][k] = (signed char)W[(k0 + k) * N_TOT + n0 + n];
  }
  __syncthreads();
  for (int i = threadIdx.x; i < 4096; i += 256) {
    int n = i >> 6, k = i & 63;
    W8T[(n0 + n) * K_TOT + k0 + k] = t[n][k];
  }
}

// out_i32 = clamp(round((X@W)*alpha + bias)) ; X int32-holding-int8 [M][K],
// W8T int8 [N][K], out int32 [M][N].
// Tile: BM=128, BN=128, BK=64; 4 waves (2x2), each wave 64x64 via 4x4 mfma_i32_16x16x64_i8.
__global__ __launch_bounds__(256, 2) void gemm_i8_kernel(
    const int* __restrict__ X, const signed char* __restrict__ W8T,
    const float* __restrict__ bias, const float* __restrict__ alpha_p,
    int* __restrict__ out) {
  __shared__ signed char Al[2][128 * 64];
  __shared__ signed char Bl[2][128 * 64];

  // XCD-chunked swizzle: dispatch d -> XCD d%8; give each XCD a contiguous
  // chunk of tiles so the 6 sibling N-tiles of one M-panel share that XCD's L2.
  const int d = blockIdx.x;
  const int t = (d & 7) * 192 + (d >> 3);   // 1536 wgs, 1536/8 = 192
  const int mt = t / 6, nt = t - mt * 6;    // n-tile fast within chunk
  const int row0 = mt << 7, col0 = nt << 7;

  const int tid = threadIdx.x;
  const int lane = tid & 63;
  const int wave = tid >> 6;
  const int wr = wave >> 1, wc = wave & 1;
  const int fr = lane & 15, fg = lane >> 4;
  const int kb = fg << 4;                    // k-byte group for fragments
  const int fsw = (fr & 3) << 4;             // frag-read XOR swizzle (row&3==fr&3)

  // A staging: thread handles 32 bytes: row = tid/2, j0 = (tid&1)*32
  const int ar = tid >> 1;
  const int aj = (tid & 1) << 5;
  const int* Xrow = X + (row0 + ar) * K_TOT + aj;
  const int asw = (ar & 3) << 4;
  const int aoff0 = ar * 64 + ((aj + 0) ^ asw);
  const int aoff1 = ar * 64 + ((aj + 16) ^ asw);

  // B staging via global_load_lds: issue i covers LDS bytes e = i*4096 + tid*16
  int bsrcoff[2];
#pragma unroll
  for (int i = 0; i < 2; ++i) {
    int e = i * 4096 + tid * 16;
    int n = e >> 6, j = e & 63;
    bsrcoff[i] = (col0 + n) * K_TOT + (j ^ ((n & 3) << 4));  // pre-swizzled source
  }

  const v4i zero = {0, 0, 0, 0};
  v4i acc[4][4];
#pragma unroll
  for (int m = 0; m < 4; ++m)
#pragma unroll
    for (int n = 0; n < 4; ++n) acc[m][n] = zero;

  // Prologue: stage K-step 0 into buf 0
  {
    v4i q[8];
    const v4i* p = (const v4i*)Xrow;
#pragma unroll
    for (int i = 0; i < 8; ++i) q[i] = p[i];
#pragma unroll
    for (int i = 0; i < 2; ++i)
      GLOAD_LDS(W8T + bsrcoff[i], &Bl[0][i * 4096 + wave * 1024]);
    unsigned pk[8];
#pragma unroll
    for (int i = 0; i < 8; ++i) pk[i] = pack4(q[i]);
    v4u w0 = {pk[0], pk[1], pk[2], pk[3]};
    v4u w1 = {pk[4], pk[5], pk[6], pk[7]};
    *(v4u*)&Al[0][aoff0] = w0;
    *(v4u*)&Al[0][aoff1] = w1;
    __syncthreads();
  }

  int buf = 0;
  for (int ks = 0; ks < 12; ++ks) {
    v4i q[8];
    const bool has_next = (ks + 1) < 12;
    if (has_next) {
      // T14: issue next-tile global loads early; HBM latency hides under MFMA
      const v4i* p = (const v4i*)(Xrow + (ks + 1) * 64);
#pragma unroll
      for (int i = 0; i < 8; ++i) q[i] = p[i];
#pragma unroll
      for (int i = 0; i < 2; ++i)
        GLOAD_LDS(W8T + bsrcoff[i] + (ks + 1) * 64,
                  &Bl[buf ^ 1][i * 4096 + wave * 1024]);
    }

    v4i af[4], bf[4];
#pragma unroll
    for (int m = 0; m < 4; ++m) {
      int r = wr * 64 + m * 16 + fr;
      af[m] = *(const v4i*)&Al[buf][r * 64 + (kb ^ fsw)];
    }
#pragma unroll
    for (int n = 0; n < 4; ++n) {
      int r = wc * 64 + n * 16 + fr;
      bf[n] = *(const v4i*)&Bl[buf][r * 64 + (kb ^ fsw)];
    }

#pragma unroll
    for (int m = 0; m < 4; ++m)
#pragma unroll
      for (int n = 0; n < 4; ++n)
        acc[m][n] = __builtin_amdgcn_mfma_i32_16x16x64_i8(af[m], bf[n], acc[m][n], 0, 0, 0);

    if (has_next) {  // write-late half of the async stage split
      unsigned pk[8];
#pragma unroll
      for (int i = 0; i < 8; ++i) pk[i] = pack4(q[i]);
      v4u w0 = {pk[0], pk[1], pk[2], pk[3]};
      v4u w1 = {pk[4], pk[5], pk[6], pk[7]};
      *(v4u*)&Al[buf ^ 1][aoff0] = w0;
      *(v4u*)&Al[buf ^ 1][aoff1] = w1;
    }
    __syncthreads();
    buf ^= 1;
  }

  // Epilogue: C/D layout col = lane&15, row = (lane>>4)*4 + reg.
  // Output buffer is INT32 (harness promotes the reference's int8 output).
  const float alpha = *alpha_p;
  float bv[4];
#pragma unroll
  for (int n = 0; n < 4; ++n) bv[n] = bias[col0 + wc * 64 + n * 16 + fr];

#pragma unroll
  for (int m = 0; m < 4; ++m) {
    int orow = row0 + wr * 64 + m * 16 + fg * 4;
#pragma unroll
    for (int n = 0; n < 4; ++n) {
      int ocol = col0 + wc * 64 + n * 16 + fr;
      int* po = out + orow * N_TOT + ocol;
#pragma unroll
      for (int r = 0; r < 4; ++r) {
        float v = rintf((float)acc[m][n][r] * alpha + bv[n]);
        v = fminf(127.f, fmaxf(-128.f, v));
        po[r * N_TOT] = (int)v;
      }
    }
  }
}

extern "C" void kernel_launch(void* const* d_in, const int* in_sizes, int n_in,
                              void* d_out, int out_size, void* d_ws, size_t ws_size,
                              hipStream_t stream) {
  const int* X = (const int*)d_in[0];        // [4,8192,768] int8 promoted to int32
  const int* W = (const int*)d_in[1];        // [768,768] int8 promoted to int32
  const float* bias = (const float*)d_in[2]; // [1,768] fp16 promoted to float32
  const float* alpha = (const float*)d_in[3];
  int* out = (int*)d_out;                    // int8 output promoted to int32
  signed char* W8T = (signed char*)d_ws;     // 768*768 = 589,824 B scratch

  dim3 pg(K_TOT / 64, N_TOT / 64);
  pack_w_kernel<<<pg, 256, 0, stream>>>(W, W8T);
  gemm_i8_kernel<<<(M_TOT / 128) * (N_TOT / 128), 256, 0, stream>>>(X, W8T, bias, alpha, out);
}